// Round 14
// baseline (341.448 us; speedup 1.0000x reference)
//
#include <hip/hip_runtime.h>
#include <hip/hip_fp16.h>
#include <stdint.h>

#define B_ 2
#define C_ 96
#define D_ 24
#define H_ 56
#define W_ 56
#define E_ 384
#define HW_ (H_*W_)        // 3136
#define S_ (D_*HW_)        // 75264
#define N_ (B_*S_)         // 150528
#define NBLK_ 2352         // N_/64 (k2 blocks)
#define WS2BLK_ 24576      // shorts per 64-pos block in fragment-ordered ws2

typedef __attribute__((ext_vector_type(8))) short bf16x8;
typedef __attribute__((ext_vector_type(4))) float f32x4;
typedef __fp16 fp16x2 __attribute__((ext_vector_type(2)));

static __device__ __forceinline__ float bf2f(unsigned short h){
    union { unsigned int u; float f; } v; v.u = ((unsigned int)h) << 16; return v.f;
}
static __device__ __forceinline__ unsigned short f2bf(float x){
    union { float f; unsigned int u; } v; v.f = x;
    unsigned int r = v.u + 0x7FFFu + ((v.u >> 16) & 1u);
    return (unsigned short)(r >> 16);
}
static __device__ __forceinline__ __half2 u2h2(unsigned int u){
    union { unsigned int u; __half2 h; } v; v.u = u; return v.h;
}
static __device__ __forceinline__ unsigned int pk_f16(float a, float b){
    union { fp16x2 h; unsigned int u; } v;
    v.h = __builtin_amdgcn_cvt_pkrtz(a, b);
    return v.u;
}
// forced packed f16 FMA: d = a*b + c elementwise on both halves
static __device__ __forceinline__ unsigned int pkfma(unsigned int a, unsigned int b, unsigned int c){
    unsigned int d;
    asm("v_pk_fma_f16 %0, %1, %2, %3" : "=v"(d) : "v"(a), "v"(b), "v"(c));
    return d;
}
// fast GELU: v*sigmoid(1.5957691*(v+0.044715 v^3)) via exp2, max |err| ~3e-4
static __device__ __forceinline__ float gelu_f(float v){
    float v2 = v*v;
    float arg = v * fmaf(v2, -0.1029432f, -2.3022080f);
    return v / (1.f + exp2f(arg));
}

// ---------------- K1 (round-12 structure, forced v_pk_fma_f16) -> ws1 -----------
// tile 8d x 8h x 56w; halo 14x14x62 staged fp16 (pitch 72, 28.2KB LDS).
// Weights: pre-packed half2(w,w) table in GLOBAL, wave-uniform index -> s_load.
__global__ __launch_bounds__(256) void k1_dwconv(
    const float* __restrict__ x, const unsigned int* __restrict__ pkwg,
    const float* __restrict__ bias, unsigned short* __restrict__ ws1)
{
    __shared__ __align__(16) unsigned short hl[14*14*72];
    const int dt = blockIdx.x / 7;   // 0..2
    const int ht = blockIdx.x - dt*7;// 0..6
    const int c  = blockIdx.y, b = blockIdx.z;
    const int d0 = dt*8, h0 = ht*8;
    const int tid = threadIdx.x;
    const float* xc = x + (size_t)(b*C_ + c) * S_;
    const unsigned int* pw = pkwg + c*343;   // block-uniform -> s_load

    for (int i = tid; i < 14*14*31; i += 256){
        int sidx = i / (14*31);
        int rem  = i - sidx*(14*31);
        int hr   = rem / 31;
        int wp   = rem - hr*31;
        int d = d0 - 3 + sidx, h = h0 - 3 + hr, w = wp*2 - 3;
        bool ok = (unsigned)d < D_ && (unsigned)h < H_;
        float v0 = (ok && (unsigned)w     < W_) ? xc[d*HW_ + h*W_ + w]   : 0.f;
        float v1 = (ok && (unsigned)(w+1) < W_) ? xc[d*HW_ + h*W_ + w+1] : 0.f;
        *(unsigned int*)&hl[(sidx*14 + hr)*72 + wp*2] = pk_f16(v0, v1);
    }
    __syncthreads();

    const int wz = tid & 7, hz = (tid >> 3) & 7, dz = tid >> 6;
    if (wz >= 7) return;

    unsigned int acc0[4] = {0,0,0,0};
    unsigned int acc1[4] = {0,0,0,0};

    for (int kh = 0; kh < 7; ++kh){
        unsigned int wprev[7];
        for (int si = 0; si < 8; ++si){
            const unsigned short* rp = &hl[((dz*2 + si)*14 + hz + kh)*72 + wz*8];
            uint4 wa = *(const uint4*)rp;
            uint2 wb = *(const uint2*)(rp + 8);
            unsigned int wcq = *(const unsigned int*)(rp + 12);
            unsigned int W[7] = {wa.x, wa.y, wa.z, wa.w, wb.x, wb.y, wcq};
            unsigned int Sh[6];
            #pragma unroll
            for (int m=0;m<6;++m) Sh[m] = __builtin_amdgcn_alignbit(W[m+1], W[m], 16);

            if (si < 7){
                unsigned int wcur[7];
                #pragma unroll
                for (int k=0;k<7;++k) wcur[k] = pw[si*49 + kh*7 + k];
                #pragma unroll
                for (int kw=0; kw<7; ++kw){
                    const int m = kw >> 1;
                    #pragma unroll
                    for (int r=0;r<4;++r){
                        unsigned int src = (kw & 1) ? Sh[m+r] : W[m+r];
                        acc0[r] = pkfma(src, wcur[kw], acc0[r]);
                    }
                }
                if (si > 0){
                    #pragma unroll
                    for (int kw=0; kw<7; ++kw){
                        const int m = kw >> 1;
                        #pragma unroll
                        for (int r=0;r<4;++r){
                            unsigned int src = (kw & 1) ? Sh[m+r] : W[m+r];
                            acc1[r] = pkfma(src, wprev[kw], acc1[r]);
                        }
                    }
                }
                #pragma unroll
                for (int k=0;k<7;++k) wprev[k] = wcur[k];
            } else {
                #pragma unroll
                for (int kw=0; kw<7; ++kw){
                    const int m = kw >> 1;
                    #pragma unroll
                    for (int r=0;r<4;++r){
                        unsigned int src = (kw & 1) ? Sh[m+r] : W[m+r];
                        acc1[r] = pkfma(src, wprev[kw], acc1[r]);
                    }
                }
            }
        }
    }

    const float bs = bias[c];
    float o0v[8], o1v[8];
    #pragma unroll
    for (int r=0;r<4;++r){
        o0v[2*r]   = __low2float(u2h2(acc0[r]))  + bs;
        o0v[2*r+1] = __high2float(u2h2(acc0[r])) + bs;
        o1v[2*r]   = __low2float(u2h2(acc1[r]))  + bs;
        o1v[2*r+1] = __high2float(u2h2(acc1[r])) + bs;
    }
    size_t o0 = (size_t)(b*C_ + c)*S_ + (size_t)(d0 + dz*2)*HW_ + (h0 + hz)*W_ + wz*8;
    unsigned int p0 = (unsigned)f2bf(o0v[0]) | ((unsigned)f2bf(o0v[1])<<16);
    unsigned int p1 = (unsigned)f2bf(o0v[2]) | ((unsigned)f2bf(o0v[3])<<16);
    unsigned int p2 = (unsigned)f2bf(o0v[4]) | ((unsigned)f2bf(o0v[5])<<16);
    unsigned int p3 = (unsigned)f2bf(o0v[6]) | ((unsigned)f2bf(o0v[7])<<16);
    *(uint4*)&ws1[o0] = make_uint4(p0,p1,p2,p3);
    p0 = (unsigned)f2bf(o1v[0]) | ((unsigned)f2bf(o1v[1])<<16);
    p1 = (unsigned)f2bf(o1v[2]) | ((unsigned)f2bf(o1v[3])<<16);
    p2 = (unsigned)f2bf(o1v[4]) | ((unsigned)f2bf(o1v[5])<<16);
    p3 = (unsigned)f2bf(o1v[6]) | ((unsigned)f2bf(o1v[7])<<16);
    *(uint4*)&ws1[o0 + HW_] = make_uint4(p0,p1,p2,p3);
}

// ---------- kw1t: w1 transpose to bf16 + dw-weight fp16x2 pack table ------------
__global__ __launch_bounds__(256) void kw1t(
    const float* __restrict__ w1, const float* __restrict__ wk,
    unsigned short* __restrict__ w1t, unsigned int* __restrict__ pkwg)
{
    int idx = blockIdx.x*256 + threadIdx.x;
    if (idx < E_*C_){
        int e = idx / C_, c = idx % C_;
        w1t[idx] = f2bf(w1[c*E_ + e]);
    }
    if (idx < 96*343){
        unsigned short us = __half_as_ushort(__float2half(wk[idx]));
        pkwg[idx] = (unsigned)us | ((unsigned)us << 16);
    }
}

// ------------- K2: LN + pwconv1(MFMA) + GELU -> ws2 (fragment-ordered) ----------
// ws2[blk][q][nt][r][lane]: store instr = 64 lanes x 2B contiguous (128B dense).
__global__ __launch_bounds__(256) void k2_ln_pw1(
    const unsigned short* __restrict__ ws1, const float* __restrict__ ln_w,
    const float* __restrict__ ln_b, const unsigned short* __restrict__ w1t,
    const float* __restrict__ b1, unsigned short* __restrict__ ws2,
    float* __restrict__ partial)
{
    __shared__ unsigned short ly[64*104];
    __shared__ float red1[256], red2[256];
    __shared__ float smu[64], srs[64];
    __shared__ float sq[4][384];
    __shared__ float b1s[384];
    const int tid = threadIdx.x;
    const int p = tid & 63, q = tid >> 6;
    const int n0 = blockIdx.x * 64;
    const int b = n0 / S_;
    const int s0 = n0 - b*S_;
    const size_t basein = (size_t)(b*C_)*S_ + s0 + p;

    for (int i = tid; i < 384; i += 256) b1s[i] = b1[i];

    float v[24];
    float sum=0.f, ssq=0.f;
    #pragma unroll
    for (int i=0;i<24;++i){
        int c = q*24 + i;
        float t = bf2f(ws1[basein + (size_t)c*S_]);
        v[i] = t; sum += t; ssq = fmaf(t,t,ssq);
    }
    red1[tid]=sum; red2[tid]=ssq;
    __syncthreads();
    if (q==0){
        float s1 = red1[p]+red1[64+p]+red1[128+p]+red1[192+p];
        float s2 = red2[p]+red2[64+p]+red2[128+p]+red2[192+p];
        float mu = s1 * (1.f/96.f);
        float var = s2*(1.f/96.f) - mu*mu;
        smu[p]=mu; srs[p]=rsqrtf(var + 1e-6f);
    }
    __syncthreads();
    {
        float mu = smu[p], rs = srs[p];
        #pragma unroll
        for (int i=0;i<24;++i){
            int c = q*24+i;
            ly[p*104 + c] = f2bf((v[i]-mu)*rs*ln_w[c] + ln_b[c]);
        }
    }
    __syncthreads();

    const int lane = tid & 63;
    const int lr = lane & 15;
    const int lk = lane >> 4;
    bf16x8 af[3];
    #pragma unroll
    for (int kk=0;kk<3;++kk)
        af[kk] = *(const bf16x8*)&ly[(q*16 + lr)*104 + kk*32 + lk*8];

    unsigned short* wout = ws2 + (size_t)blockIdx.x*WS2BLK_ + q*6144 + lane;

    for (int nt=0; nt<24; ++nt){
        f32x4 acc = {0.f,0.f,0.f,0.f};
        #pragma unroll
        for (int kk=0;kk<3;++kk){
            bf16x8 bfr = *(const bf16x8*)&w1t[(size_t)(nt*16 + lr)*C_ + kk*32 + lk*8];
            acc = __builtin_amdgcn_mfma_f32_16x16x32_bf16(af[kk], bfr, acc, 0, 0, 0);
        }
        float bias = b1s[nt*16 + lr];
        float ps = 0.f;
        #pragma unroll
        for (int r=0;r<4;++r){
            float val = acc[r] + bias;
            float g = gelu_f(val);
            ps = fmaf(g,g,ps);
            wout[nt*256 + r*64] = f2bf(g);
        }
        ps += __shfl_xor(ps, 16);
        ps += __shfl_xor(ps, 32);
        if (lane < 16) sq[q][nt*16 + lane] = ps;
    }
    __syncthreads();
    // transposed partial: [e][NBLK_]; 2 scattered 4B stores per thread (L2-merged)
    for (int i = tid; i < 384; i += 256)
        partial[(size_t)i*NBLK_ + blockIdx.x] = sq[0][i]+sq[1][i]+sq[2][i]+sq[3][i];
}

// ---------- K3a: contiguous reduce of partial -> GRN scale sscale[b][e] ---------
__global__ __launch_bounds__(384) void k3a(
    const float* __restrict__ partial, const float* __restrict__ gamma,
    float* __restrict__ sscale)
{
    const int b = blockIdx.x, e = threadIdx.x;
    const float4* p4 = (const float4*)(partial + (size_t)e*NBLK_ + b*(NBLK_/2));
    float s = 0.f;
    for (int i=0;i<NBLK_/8;++i){           // 294 float4 = 1176 floats
        float4 t = p4[i];
        s += t.x + t.y + t.z + t.w;
    }
    s = fmaxf(s, 0.f);                      // NaN insurance
    float g = sqrtf(s);
    float vsum = g;
    #pragma unroll
    for (int off=32; off; off>>=1) vsum += __shfl_down(vsum, off);
    __shared__ float r[6];
    __shared__ float mean_s;
    if ((e & 63)==0) r[e>>6] = vsum;
    __syncthreads();
    if (e==0) mean_s = (r[0]+r[1]+r[2]+r[3]+r[4]+r[5]) * (1.f/384.f);
    __syncthreads();
    sscale[b*E_ + e] = 1.f + gamma[e] * (g / (mean_s + 1e-6f));
}

// ---------- kw2s: parallel w2s[b][c][e] = w2[e][c]*sscale[b][e] ------------------
__global__ __launch_bounds__(256) void kw2s(
    const float* __restrict__ w2, const float* __restrict__ sscale,
    unsigned short* __restrict__ w2s)
{
    int idx = blockIdx.x*256 + threadIdx.x;   // 288 blocks x 256 = 73728
    int b = idx / (C_*E_);
    int rem = idx - b*(C_*E_);
    int c = rem / E_, e = rem - (rem/E_)*E_;
    w2s[idx] = f2bf(w2[e*C_ + c] * sscale[b*E_ + e]);
}

// ---------- k3c: bc[j] = b2[j] + sum_e beta[e]*w2[e,j], 96 parallel blocks ------
__global__ __launch_bounds__(64) void k3c_bc(
    const float* __restrict__ b2, const float* __restrict__ beta,
    const float* __restrict__ w2, float* __restrict__ bc)
{
    const int j = blockIdx.x, lane = threadIdx.x;
    float a = 0.f;
    #pragma unroll
    for (int r=0;r<6;++r){
        int e = lane*6 + r;
        a = fmaf(beta[e], w2[e*C_ + j], a);
    }
    #pragma unroll
    for (int off=32; off; off>>=1) a += __shfl_down(a, off);
    if (lane==0) bc[j] = b2[j] + a;
}

// ---------- K4: pwconv2 (MFMA), fragment-ordered ws2 reads ----------------------
__global__ __launch_bounds__(256) void k4_pw2(
    const unsigned short* __restrict__ ws2, const unsigned short* __restrict__ w2s,
    const float* __restrict__ bc, const float* __restrict__ x,
    float* __restrict__ out)
{
    const int tid = threadIdx.x;
    const int n0 = blockIdx.x * 128;
    const int b = n0 / S_;
    const int s0 = n0 - b*S_;
    const int lane = tid & 63, q = tid >> 6;
    const int lr = lane & 15, lk = lane >> 4;

    f32x4 acc0[6], acc1[6];
    #pragma unroll
    for (int m=0;m<6;++m){ acc0[m] = (f32x4){0,0,0,0}; acc1[m] = (f32x4){0,0,0,0}; }
    const unsigned short* w2sb = w2s + (size_t)b*C_*E_;
    // fragment-ordered ws2: lane offset within block
    const unsigned short* base0 = ws2 + (size_t)(blockIdx.x*2)*WS2BLK_
                                + q*6144 + (lr&3)*64 + (lr>>2)*16 + (lk&1)*8;

    for (int kk=0; kk<12; ++kk){
        const int off = (2*kk + (lk>>1))*256;
        bf16x8 bfr0 = *(const bf16x8*)&base0[off];
        bf16x8 bfr1 = *(const bf16x8*)&base0[WS2BLK_ + off];
        #pragma unroll
        for (int m=0;m<6;++m){
            bf16x8 afr = *(const bf16x8*)&w2sb[(size_t)(m*16 + lr)*E_ + kk*32 + lk*8];
            acc0[m] = __builtin_amdgcn_mfma_f32_16x16x32_bf16(afr, bfr0, acc0[m], 0, 0, 0);
            acc1[m] = __builtin_amdgcn_mfma_f32_16x16x32_bf16(afr, bfr1, acc1[m], 0, 0, 0);
        }
    }

    const int pos = q*16 + lr;
    const size_t sidx0 = (size_t)s0 + pos;
    #pragma unroll
    for (int m=0;m<6;++m){
        #pragma unroll
        for (int r=0;r<4;++r){
            int c = m*16 + lk*4 + r;
            float bcv = bc[c];
            size_t a0 = ((size_t)(b*C_ + c))*S_ + sidx0;
            out[a0]      = acc0[m][r] + bcv + x[a0];
            out[a0 + 64] = acc1[m][r] + bcv + x[a0 + 64];
        }
    }
}

extern "C" void kernel_launch(void* const* d_in, const int* in_sizes, int n_in,
                              void* d_out, int out_size, void* d_ws, size_t ws_size,
                              hipStream_t stream)
{
    const float* x     = (const float*)d_in[0];
    const float* dwk   = (const float*)d_in[1];
    const float* dwb   = (const float*)d_in[2];
    const float* ln_w  = (const float*)d_in[3];
    const float* ln_b  = (const float*)d_in[4];
    const float* w1    = (const float*)d_in[5];
    const float* b1    = (const float*)d_in[6];
    const float* gamma = (const float*)d_in[7];
    const float* beta  = (const float*)d_in[8];
    const float* w2    = (const float*)d_in[9];
    const float* b2    = (const float*)d_in[10];
    float* out = (float*)d_out;

    char* ws = (char*)d_ws;
    unsigned short* ws1 = (unsigned short*)ws;                        // 28.9 MB used
    unsigned short* ws2 = (unsigned short*)(ws + 57802752);           // 115.6 MB
    unsigned short* w1t = (unsigned short*)(ws + 173408256);          // 73,728 B
    float* sscale = (float*)(ws + 173408256 + 73728);                 // 3,072 B
    float* bc     = sscale + B_*E_;                                   // 384 B
    // aliased into ws1 region (ws1 dead after k2; written after k2):
    unsigned short* w2s = (unsigned short*)ws;                        // 294,912 B
    // d_out region as scratch (k4 fully overwrites it afterwards):
    float* partial = (float*)d_out;                                   // 3,612,672 B
    unsigned int* pkwg = (unsigned int*)((char*)d_out + 4194304);     // 131,712 B

    kw1t      <<<dim3(144),     256, 0, stream>>>(w1, dwk, w1t, pkwg);
    k1_dwconv <<<dim3(21,96,2), 256, 0, stream>>>(x, pkwg, dwb, ws1);
    k2_ln_pw1 <<<dim3(NBLK_),   256, 0, stream>>>(ws1, ln_w, ln_b, w1t, b1, ws2, partial);
    k3a       <<<dim3(2),       384, 0, stream>>>(partial, gamma, sscale);
    kw2s      <<<dim3(288),     256, 0, stream>>>(w2, sscale, w2s);
    k3c_bc    <<<dim3(96),       64, 0, stream>>>(b2, beta, w2, bc);
    k4_pw2    <<<dim3(N_/128),  256, 0, stream>>>(ws2, w2s, bc, x, out);
}

// Round 15
// 340.620 us; speedup vs baseline: 1.0024x; 1.0024x over previous
//
#include <hip/hip_runtime.h>
#include <hip/hip_fp16.h>
#include <stdint.h>

#define B_ 2
#define C_ 96
#define D_ 24
#define H_ 56
#define W_ 56
#define E_ 384
#define HW_ (H_*W_)        // 3136
#define S_ (D_*HW_)        // 75264
#define N_ (B_*S_)         // 150528
#define NBLK_ 2352         // N_/64 (k2 blocks)
#define WS2BLK_ 24576      // shorts per 64-pos block in fragment-ordered ws2

typedef __attribute__((ext_vector_type(8))) short bf16x8;
typedef __attribute__((ext_vector_type(4))) float f32x4;
typedef __fp16 fp16x2 __attribute__((ext_vector_type(2)));

static __device__ __forceinline__ float bf2f(unsigned short h){
    union { unsigned int u; float f; } v; v.u = ((unsigned int)h) << 16; return v.f;
}
static __device__ __forceinline__ unsigned short f2bf(float x){
    union { float f; unsigned int u; } v; v.f = x;
    unsigned int r = v.u + 0x7FFFu + ((v.u >> 16) & 1u);
    return (unsigned short)(r >> 16);
}
static __device__ __forceinline__ __half2 u2h2(unsigned int u){
    union { unsigned int u; __half2 h; } v; v.u = u; return v.h;
}
static __device__ __forceinline__ unsigned int pk_f16(float a, float b){
    union { fp16x2 h; unsigned int u; } v;
    v.h = __builtin_amdgcn_cvt_pkrtz(a, b);
    return v.u;
}
// tied-operand packed f16 FMA: acc = a*b + acc (D==C register, no copies)
static __device__ __forceinline__ void pkfma(unsigned int& acc, unsigned int a, unsigned int b){
    asm("v_pk_fma_f16 %0, %1, %2, %0" : "+v"(acc) : "v"(a), "v"(b));
}
// fast GELU: v*sigmoid(1.5957691*(v+0.044715 v^3)) via exp2, max |err| ~3e-4
static __device__ __forceinline__ float gelu_f(float v){
    float v2 = v*v;
    float arg = v * fmaf(v2, -0.1029432f, -2.3022080f);
    return v / (1.f + exp2f(arg));
}

// ---------------- K1 (round-12 structure, TIED v_pk_fma_f16) -> ws1 -------------
// tile 8d x 8h x 56w; halo 14x14x62 staged fp16 (pitch 72, 28.2KB LDS).
// Weights: pre-packed half2(w,w) table in GLOBAL, wave-uniform index -> s_load.
__global__ __launch_bounds__(256) void k1_dwconv(
    const float* __restrict__ x, const unsigned int* __restrict__ pkwg,
    const float* __restrict__ bias, unsigned short* __restrict__ ws1)
{
    __shared__ __align__(16) unsigned short hl[14*14*72];
    const int dt = blockIdx.x / 7;   // 0..2
    const int ht = blockIdx.x - dt*7;// 0..6
    const int c  = blockIdx.y, b = blockIdx.z;
    const int d0 = dt*8, h0 = ht*8;
    const int tid = threadIdx.x;
    const float* xc = x + (size_t)(b*C_ + c) * S_;
    const unsigned int* pw = pkwg + c*343;   // block-uniform -> s_load

    for (int i = tid; i < 14*14*31; i += 256){
        int sidx = i / (14*31);
        int rem  = i - sidx*(14*31);
        int hr   = rem / 31;
        int wp   = rem - hr*31;
        int d = d0 - 3 + sidx, h = h0 - 3 + hr, w = wp*2 - 3;
        bool ok = (unsigned)d < D_ && (unsigned)h < H_;
        float v0 = (ok && (unsigned)w     < W_) ? xc[d*HW_ + h*W_ + w]   : 0.f;
        float v1 = (ok && (unsigned)(w+1) < W_) ? xc[d*HW_ + h*W_ + w+1] : 0.f;
        *(unsigned int*)&hl[(sidx*14 + hr)*72 + wp*2] = pk_f16(v0, v1);
    }
    __syncthreads();

    const int wz = tid & 7, hz = (tid >> 3) & 7, dz = tid >> 6;
    if (wz >= 7) return;

    unsigned int acc0[4] = {0,0,0,0};
    unsigned int acc1[4] = {0,0,0,0};

    for (int kh = 0; kh < 7; ++kh){
        unsigned int wprev[7];
        for (int si = 0; si < 8; ++si){
            const unsigned short* rp = &hl[((dz*2 + si)*14 + hz + kh)*72 + wz*8];
            uint4 wa = *(const uint4*)rp;
            uint2 wb = *(const uint2*)(rp + 8);
            unsigned int wcq = *(const unsigned int*)(rp + 12);
            unsigned int W[7] = {wa.x, wa.y, wa.z, wa.w, wb.x, wb.y, wcq};
            unsigned int Sh[6];
            #pragma unroll
            for (int m=0;m<6;++m) Sh[m] = __builtin_amdgcn_alignbit(W[m+1], W[m], 16);

            if (si < 7){
                unsigned int wcur[7];
                #pragma unroll
                for (int k=0;k<7;++k) wcur[k] = pw[si*49 + kh*7 + k];
                #pragma unroll
                for (int kw=0; kw<7; ++kw){
                    const int m = kw >> 1;
                    #pragma unroll
                    for (int r=0;r<4;++r)
                        pkfma(acc0[r], (kw & 1) ? Sh[m+r] : W[m+r], wcur[kw]);
                }
                if (si > 0){
                    #pragma unroll
                    for (int kw=0; kw<7; ++kw){
                        const int m = kw >> 1;
                        #pragma unroll
                        for (int r=0;r<4;++r)
                            pkfma(acc1[r], (kw & 1) ? Sh[m+r] : W[m+r], wprev[kw]);
                    }
                }
                #pragma unroll
                for (int k=0;k<7;++k) wprev[k] = wcur[k];
            } else {
                #pragma unroll
                for (int kw=0; kw<7; ++kw){
                    const int m = kw >> 1;
                    #pragma unroll
                    for (int r=0;r<4;++r)
                        pkfma(acc1[r], (kw & 1) ? Sh[m+r] : W[m+r], wprev[kw]);
                }
            }
        }
    }

    const float bs = bias[c];
    float o0v[8], o1v[8];
    #pragma unroll
    for (int r=0;r<4;++r){
        o0v[2*r]   = __low2float(u2h2(acc0[r]))  + bs;
        o0v[2*r+1] = __high2float(u2h2(acc0[r])) + bs;
        o1v[2*r]   = __low2float(u2h2(acc1[r]))  + bs;
        o1v[2*r+1] = __high2float(u2h2(acc1[r])) + bs;
    }
    size_t o0 = (size_t)(b*C_ + c)*S_ + (size_t)(d0 + dz*2)*HW_ + (h0 + hz)*W_ + wz*8;
    unsigned int p0 = (unsigned)f2bf(o0v[0]) | ((unsigned)f2bf(o0v[1])<<16);
    unsigned int p1 = (unsigned)f2bf(o0v[2]) | ((unsigned)f2bf(o0v[3])<<16);
    unsigned int p2 = (unsigned)f2bf(o0v[4]) | ((unsigned)f2bf(o0v[5])<<16);
    unsigned int p3 = (unsigned)f2bf(o0v[6]) | ((unsigned)f2bf(o0v[7])<<16);
    *(uint4*)&ws1[o0] = make_uint4(p0,p1,p2,p3);
    p0 = (unsigned)f2bf(o1v[0]) | ((unsigned)f2bf(o1v[1])<<16);
    p1 = (unsigned)f2bf(o1v[2]) | ((unsigned)f2bf(o1v[3])<<16);
    p2 = (unsigned)f2bf(o1v[4]) | ((unsigned)f2bf(o1v[5])<<16);
    p3 = (unsigned)f2bf(o1v[6]) | ((unsigned)f2bf(o1v[7])<<16);
    *(uint4*)&ws1[o0 + HW_] = make_uint4(p0,p1,p2,p3);
}

// ---------- kw1t: w1 transpose to bf16 + dw-weight fp16x2 pack table ------------
__global__ __launch_bounds__(256) void kw1t(
    const float* __restrict__ w1, const float* __restrict__ wk,
    unsigned short* __restrict__ w1t, unsigned int* __restrict__ pkwg)
{
    int idx = blockIdx.x*256 + threadIdx.x;
    if (idx < E_*C_){
        int e = idx / C_, c = idx % C_;
        w1t[idx] = f2bf(w1[c*E_ + e]);
    }
    if (idx < 96*343){
        unsigned short us = __half_as_ushort(__float2half(wk[idx]));
        pkwg[idx] = (unsigned)us | ((unsigned)us << 16);
    }
}

// ------------- K2: LN + pwconv1(MFMA) + GELU -> ws2 (fragment-ordered) ----------
// ws2[blk][q][nt][r][lane]: store instr = 64 lanes x 2B contiguous (128B dense).
__global__ __launch_bounds__(256) void k2_ln_pw1(
    const unsigned short* __restrict__ ws1, const float* __restrict__ ln_w,
    const float* __restrict__ ln_b, const unsigned short* __restrict__ w1t,
    const float* __restrict__ b1, unsigned short* __restrict__ ws2,
    float* __restrict__ partial)
{
    __shared__ unsigned short ly[64*104];
    __shared__ float red1[256], red2[256];
    __shared__ float smu[64], srs[64];
    __shared__ float sq[4][384];
    __shared__ float b1s[384];
    const int tid = threadIdx.x;
    const int p = tid & 63, q = tid >> 6;
    const int n0 = blockIdx.x * 64;
    const int b = n0 / S_;
    const int s0 = n0 - b*S_;
    const size_t basein = (size_t)(b*C_)*S_ + s0 + p;

    for (int i = tid; i < 384; i += 256) b1s[i] = b1[i];

    float v[24];
    float sum=0.f, ssq=0.f;
    #pragma unroll
    for (int i=0;i<24;++i){
        int c = q*24 + i;
        float t = bf2f(ws1[basein + (size_t)c*S_]);
        v[i] = t; sum += t; ssq = fmaf(t,t,ssq);
    }
    red1[tid]=sum; red2[tid]=ssq;
    __syncthreads();
    if (q==0){
        float s1 = red1[p]+red1[64+p]+red1[128+p]+red1[192+p];
        float s2 = red2[p]+red2[64+p]+red2[128+p]+red2[192+p];
        float mu = s1 * (1.f/96.f);
        float var = s2*(1.f/96.f) - mu*mu;
        smu[p]=mu; srs[p]=rsqrtf(var + 1e-6f);
    }
    __syncthreads();
    {
        float mu = smu[p], rs = srs[p];
        #pragma unroll
        for (int i=0;i<24;++i){
            int c = q*24+i;
            ly[p*104 + c] = f2bf((v[i]-mu)*rs*ln_w[c] + ln_b[c]);
        }
    }
    __syncthreads();

    const int lane = tid & 63;
    const int lr = lane & 15;
    const int lk = lane >> 4;
    bf16x8 af[3];
    #pragma unroll
    for (int kk=0;kk<3;++kk)
        af[kk] = *(const bf16x8*)&ly[(q*16 + lr)*104 + kk*32 + lk*8];

    unsigned short* wout = ws2 + (size_t)blockIdx.x*WS2BLK_ + q*6144 + lane;

    for (int nt=0; nt<24; ++nt){
        f32x4 acc = {0.f,0.f,0.f,0.f};
        #pragma unroll
        for (int kk=0;kk<3;++kk){
            bf16x8 bfr = *(const bf16x8*)&w1t[(size_t)(nt*16 + lr)*C_ + kk*32 + lk*8];
            acc = __builtin_amdgcn_mfma_f32_16x16x32_bf16(af[kk], bfr, acc, 0, 0, 0);
        }
        float bias = b1s[nt*16 + lr];
        float ps = 0.f;
        #pragma unroll
        for (int r=0;r<4;++r){
            float val = acc[r] + bias;
            float g = gelu_f(val);
            ps = fmaf(g,g,ps);
            wout[nt*256 + r*64] = f2bf(g);
        }
        ps += __shfl_xor(ps, 16);
        ps += __shfl_xor(ps, 32);
        if (lane < 16) sq[q][nt*16 + lane] = ps;
    }
    __syncthreads();
    // transposed partial: [e][NBLK_]; 2 scattered 4B stores per thread (L2-merged)
    for (int i = tid; i < 384; i += 256)
        partial[(size_t)i*NBLK_ + blockIdx.x] = sq[0][i]+sq[1][i]+sq[2][i]+sq[3][i];
}

// ---------- K3a: contiguous reduce of partial -> GRN scale sscale[b][e] ---------
__global__ __launch_bounds__(384) void k3a(
    const float* __restrict__ partial, const float* __restrict__ gamma,
    float* __restrict__ sscale)
{
    const int b = blockIdx.x, e = threadIdx.x;
    const float4* p4 = (const float4*)(partial + (size_t)e*NBLK_ + b*(NBLK_/2));
    float s = 0.f;
    for (int i=0;i<NBLK_/8;++i){           // 294 float4 = 1176 floats
        float4 t = p4[i];
        s += t.x + t.y + t.z + t.w;
    }
    s = fmaxf(s, 0.f);                      // NaN insurance
    float g = sqrtf(s);
    float vsum = g;
    #pragma unroll
    for (int off=32; off; off>>=1) vsum += __shfl_down(vsum, off);
    __shared__ float r[6];
    __shared__ float mean_s;
    if ((e & 63)==0) r[e>>6] = vsum;
    __syncthreads();
    if (e==0) mean_s = (r[0]+r[1]+r[2]+r[3]+r[4]+r[5]) * (1.f/384.f);
    __syncthreads();
    sscale[b*E_ + e] = 1.f + gamma[e] * (g / (mean_s + 1e-6f));
}

// ---------- kw2s: parallel w2s[b][c][e] = w2[e][c]*sscale[b][e] ------------------
__global__ __launch_bounds__(256) void kw2s(
    const float* __restrict__ w2, const float* __restrict__ sscale,
    unsigned short* __restrict__ w2s)
{
    int idx = blockIdx.x*256 + threadIdx.x;   // 288 blocks x 256 = 73728
    int b = idx / (C_*E_);
    int rem = idx - b*(C_*E_);
    int c = rem / E_, e = rem - (rem/E_)*E_;
    w2s[idx] = f2bf(w2[e*C_ + c] * sscale[b*E_ + e]);
}

// ---------- k3c: bc[j] = b2[j] + sum_e beta[e]*w2[e,j], 96 parallel blocks ------
__global__ __launch_bounds__(64) void k3c_bc(
    const float* __restrict__ b2, const float* __restrict__ beta,
    const float* __restrict__ w2, float* __restrict__ bc)
{
    const int j = blockIdx.x, lane = threadIdx.x;
    float a = 0.f;
    #pragma unroll
    for (int r=0;r<6;++r){
        int e = lane*6 + r;
        a = fmaf(beta[e], w2[e*C_ + j], a);
    }
    #pragma unroll
    for (int off=32; off; off>>=1) a += __shfl_down(a, off);
    if (lane==0) bc[j] = b2[j] + a;
}

// ---------- K4: pwconv2 (MFMA), fragment-ordered ws2 reads ----------------------
__global__ __launch_bounds__(256) void k4_pw2(
    const unsigned short* __restrict__ ws2, const unsigned short* __restrict__ w2s,
    const float* __restrict__ bc, const float* __restrict__ x,
    float* __restrict__ out)
{
    const int tid = threadIdx.x;
    const int n0 = blockIdx.x * 128;
    const int b = n0 / S_;
    const int s0 = n0 - b*S_;
    const int lane = tid & 63, q = tid >> 6;
    const int lr = lane & 15, lk = lane >> 4;

    f32x4 acc0[6], acc1[6];
    #pragma unroll
    for (int m=0;m<6;++m){ acc0[m] = (f32x4){0,0,0,0}; acc1[m] = (f32x4){0,0,0,0}; }
    const unsigned short* w2sb = w2s + (size_t)b*C_*E_;
    // fragment-ordered ws2: lane offset within block
    const unsigned short* base0 = ws2 + (size_t)(blockIdx.x*2)*WS2BLK_
                                + q*6144 + (lr&3)*64 + (lr>>2)*16 + (lk&1)*8;

    for (int kk=0; kk<12; ++kk){
        const int off = (2*kk + (lk>>1))*256;
        bf16x8 bfr0 = *(const bf16x8*)&base0[off];
        bf16x8 bfr1 = *(const bf16x8*)&base0[WS2BLK_ + off];
        #pragma unroll
        for (int m=0;m<6;++m){
            bf16x8 afr = *(const bf16x8*)&w2sb[(size_t)(m*16 + lr)*E_ + kk*32 + lk*8];
            acc0[m] = __builtin_amdgcn_mfma_f32_16x16x32_bf16(afr, bfr0, acc0[m], 0, 0, 0);
            acc1[m] = __builtin_amdgcn_mfma_f32_16x16x32_bf16(afr, bfr1, acc1[m], 0, 0, 0);
        }
    }

    const int pos = q*16 + lr;
    const size_t sidx0 = (size_t)s0 + pos;
    #pragma unroll
    for (int m=0;m<6;++m){
        #pragma unroll
        for (int r=0;r<4;++r){
            int c = m*16 + lk*4 + r;
            float bcv = bc[c];
            size_t a0 = ((size_t)(b*C_ + c))*S_ + sidx0;
            out[a0]      = acc0[m][r] + bcv + x[a0];
            out[a0 + 64] = acc1[m][r] + bcv + x[a0 + 64];
        }
    }
}

extern "C" void kernel_launch(void* const* d_in, const int* in_sizes, int n_in,
                              void* d_out, int out_size, void* d_ws, size_t ws_size,
                              hipStream_t stream)
{
    const float* x     = (const float*)d_in[0];
    const float* dwk   = (const float*)d_in[1];
    const float* dwb   = (const float*)d_in[2];
    const float* ln_w  = (const float*)d_in[3];
    const float* ln_b  = (const float*)d_in[4];
    const float* w1    = (const float*)d_in[5];
    const float* b1    = (const float*)d_in[6];
    const float* gamma = (const float*)d_in[7];
    const float* beta  = (const float*)d_in[8];
    const float* w2    = (const float*)d_in[9];
    const float* b2    = (const float*)d_in[10];
    float* out = (float*)d_out;

    char* ws = (char*)d_ws;
    unsigned short* ws1 = (unsigned short*)ws;                        // 28.9 MB used
    unsigned short* ws2 = (unsigned short*)(ws + 57802752);           // 115.6 MB
    unsigned short* w1t = (unsigned short*)(ws + 173408256);          // 73,728 B
    float* sscale = (float*)(ws + 173408256 + 73728);                 // 3,072 B
    float* bc     = sscale + B_*E_;                                   // 384 B
    // aliased into ws1 region (ws1 dead after k2; written after k2):
    unsigned short* w2s = (unsigned short*)ws;                        // 294,912 B
    // d_out region as scratch (k4 fully overwrites it afterwards):
    float* partial = (float*)d_out;                                   // 3,612,672 B
    unsigned int* pkwg = (unsigned int*)((char*)d_out + 4194304);     // 131,712 B

    kw1t      <<<dim3(144),     256, 0, stream>>>(w1, dwk, w1t, pkwg);
    k1_dwconv <<<dim3(21,96,2), 256, 0, stream>>>(x, pkwg, dwb, ws1);
    k2_ln_pw1 <<<dim3(NBLK_),   256, 0, stream>>>(ws1, ln_w, ln_b, w1t, b1, ws2, partial);
    k3a       <<<dim3(2),       384, 0, stream>>>(partial, gamma, sscale);
    kw2s      <<<dim3(288),     256, 0, stream>>>(w2, sscale, w2s);
    k3c_bc    <<<dim3(96),       64, 0, stream>>>(b2, beta, w2, bc);
    k4_pw2    <<<dim3(N_/128),  256, 0, stream>>>(ws2, w2s, bc, x, out);
}

// Round 16
// 291.288 us; speedup vs baseline: 1.1722x; 1.1694x over previous
//
#include <hip/hip_runtime.h>
#include <hip/hip_fp16.h>
#include <stdint.h>

#define B_ 2
#define C_ 96
#define D_ 24
#define H_ 56
#define W_ 56
#define E_ 384
#define HW_ (H_*W_)        // 3136
#define S_ (D_*HW_)        // 75264
#define N_ (B_*S_)         // 150528
#define NBLK_ 2352         // N_/64 (k2 blocks)
#define WS2BLK_ 24576      // shorts per 64-pos block in fragment-ordered ws2

typedef __attribute__((ext_vector_type(8))) short bf16x8;
typedef __attribute__((ext_vector_type(4))) float f32x4;
typedef __fp16 fp16x2 __attribute__((ext_vector_type(2)));

static __device__ __forceinline__ float bf2f(unsigned short h){
    union { unsigned int u; float f; } v; v.u = ((unsigned int)h) << 16; return v.f;
}
static __device__ __forceinline__ unsigned short f2bf(float x){
    union { float f; unsigned int u; } v; v.f = x;
    unsigned int r = v.u + 0x7FFFu + ((v.u >> 16) & 1u);
    return (unsigned short)(r >> 16);
}
static __device__ __forceinline__ __half2 u2h2(unsigned int u){
    union { unsigned int u; __half2 h; } v; v.u = u; return v.h;
}
static __device__ __forceinline__ unsigned int pk_f16(float a, float b){
    union { fp16x2 h; unsigned int u; } v;
    v.h = __builtin_amdgcn_cvt_pkrtz(a, b);
    return v.u;
}
// fast GELU: v*sigmoid(1.5957691*(v+0.044715 v^3)) via exp2, max |err| ~3e-4
static __device__ __forceinline__ float gelu_f(float v){
    float v2 = v*v;
    float arg = v * fmaf(v2, -0.1029432f, -2.3022080f);
    return v / (1.f + exp2f(arg));
}

// ---------------- K1 (r12-proven): dw conv 8d x 8h x 56w, __hfma2 -> ws1 --------
// halo 14x14x62 staged fp16 (pitch 72, 28.2KB LDS); weights = packed half2(w,w)
// table in GLOBAL, wave-uniform index -> s_load.
__global__ __launch_bounds__(256) void k1_dwconv(
    const float* __restrict__ x, const unsigned int* __restrict__ pkwg,
    const float* __restrict__ bias, unsigned short* __restrict__ ws1)
{
    __shared__ __align__(16) unsigned short hl[14*14*72];
    const int dt = blockIdx.x / 7;   // 0..2
    const int ht = blockIdx.x - dt*7;// 0..6
    const int c  = blockIdx.y, b = blockIdx.z;
    const int d0 = dt*8, h0 = ht*8;
    const int tid = threadIdx.x;
    const float* xc = x + (size_t)(b*C_ + c) * S_;
    const unsigned int* pw = pkwg + c*343;   // block-uniform -> s_load

    for (int i = tid; i < 14*14*31; i += 256){
        int sidx = i / (14*31);
        int rem  = i - sidx*(14*31);
        int hr   = rem / 31;
        int wp   = rem - hr*31;
        int d = d0 - 3 + sidx, h = h0 - 3 + hr, w = wp*2 - 3;
        bool ok = (unsigned)d < D_ && (unsigned)h < H_;
        float v0 = (ok && (unsigned)w     < W_) ? xc[d*HW_ + h*W_ + w]   : 0.f;
        float v1 = (ok && (unsigned)(w+1) < W_) ? xc[d*HW_ + h*W_ + w+1] : 0.f;
        *(unsigned int*)&hl[(sidx*14 + hr)*72 + wp*2] = pk_f16(v0, v1);
    }
    __syncthreads();

    const int wz = tid & 7, hz = (tid >> 3) & 7, dz = tid >> 6;
    if (wz >= 7) return;

    __half2 acc0[4], acc1[4];
    #pragma unroll
    for (int r=0;r<4;++r){ acc0[r] = u2h2(0u); acc1[r] = u2h2(0u); }

    for (int kh = 0; kh < 7; ++kh){
        unsigned int wprev[7];
        for (int si = 0; si < 8; ++si){
            const unsigned short* rp = &hl[((dz*2 + si)*14 + hz + kh)*72 + wz*8];
            uint4 wa = *(const uint4*)rp;
            uint2 wb = *(const uint2*)(rp + 8);
            unsigned int wcq = *(const unsigned int*)(rp + 12);
            unsigned int W[7] = {wa.x, wa.y, wa.z, wa.w, wb.x, wb.y, wcq};
            unsigned int Sh[6];
            #pragma unroll
            for (int m=0;m<6;++m) Sh[m] = __builtin_amdgcn_alignbit(W[m+1], W[m], 16);

            if (si < 7){
                unsigned int wcur[7];
                #pragma unroll
                for (int k=0;k<7;++k) wcur[k] = pw[si*49 + kh*7 + k];
                #pragma unroll
                for (int kw=0; kw<7; ++kw){
                    const int m = kw >> 1;
                    __half2 wp = u2h2(wcur[kw]);
                    #pragma unroll
                    for (int r=0;r<4;++r){
                        __half2 src = (kw & 1) ? u2h2(Sh[m+r]) : u2h2(W[m+r]);
                        acc0[r] = __hfma2(src, wp, acc0[r]);
                    }
                }
                if (si > 0){
                    #pragma unroll
                    for (int kw=0; kw<7; ++kw){
                        const int m = kw >> 1;
                        __half2 wp = u2h2(wprev[kw]);
                        #pragma unroll
                        for (int r=0;r<4;++r){
                            __half2 src = (kw & 1) ? u2h2(Sh[m+r]) : u2h2(W[m+r]);
                            acc1[r] = __hfma2(src, wp, acc1[r]);
                        }
                    }
                }
                #pragma unroll
                for (int k=0;k<7;++k) wprev[k] = wcur[k];
            } else {
                #pragma unroll
                for (int kw=0; kw<7; ++kw){
                    const int m = kw >> 1;
                    __half2 wp = u2h2(wprev[kw]);
                    #pragma unroll
                    for (int r=0;r<4;++r){
                        __half2 src = (kw & 1) ? u2h2(Sh[m+r]) : u2h2(W[m+r]);
                        acc1[r] = __hfma2(src, wp, acc1[r]);
                    }
                }
            }
        }
    }

    const float bs = bias[c];
    float o0v[8], o1v[8];
    #pragma unroll
    for (int r=0;r<4;++r){
        o0v[2*r]   = __low2float(acc0[r])  + bs;
        o0v[2*r+1] = __high2float(acc0[r]) + bs;
        o1v[2*r]   = __low2float(acc1[r])  + bs;
        o1v[2*r+1] = __high2float(acc1[r]) + bs;
    }
    size_t o0 = (size_t)(b*C_ + c)*S_ + (size_t)(d0 + dz*2)*HW_ + (h0 + hz)*W_ + wz*8;
    unsigned int p0 = (unsigned)f2bf(o0v[0]) | ((unsigned)f2bf(o0v[1])<<16);
    unsigned int p1 = (unsigned)f2bf(o0v[2]) | ((unsigned)f2bf(o0v[3])<<16);
    unsigned int p2 = (unsigned)f2bf(o0v[4]) | ((unsigned)f2bf(o0v[5])<<16);
    unsigned int p3 = (unsigned)f2bf(o0v[6]) | ((unsigned)f2bf(o0v[7])<<16);
    *(uint4*)&ws1[o0] = make_uint4(p0,p1,p2,p3);
    p0 = (unsigned)f2bf(o1v[0]) | ((unsigned)f2bf(o1v[1])<<16);
    p1 = (unsigned)f2bf(o1v[2]) | ((unsigned)f2bf(o1v[3])<<16);
    p2 = (unsigned)f2bf(o1v[4]) | ((unsigned)f2bf(o1v[5])<<16);
    p3 = (unsigned)f2bf(o1v[6]) | ((unsigned)f2bf(o1v[7])<<16);
    *(uint4*)&ws1[o0 + HW_] = make_uint4(p0,p1,p2,p3);
}

// ---------- kw1t: w1 transpose to bf16 + dw-weight fp16x2 pack table ------------
__global__ __launch_bounds__(256) void kw1t(
    const float* __restrict__ w1, const float* __restrict__ wk,
    unsigned short* __restrict__ w1t, unsigned int* __restrict__ pkwg)
{
    int idx = blockIdx.x*256 + threadIdx.x;
    if (idx < E_*C_){
        int e = idx / C_, c = idx % C_;
        w1t[idx] = f2bf(w1[c*E_ + e]);
    }
    if (idx < 96*343){
        unsigned short us = __half_as_ushort(__float2half(wk[idx]));
        pkwg[idx] = (unsigned)us | ((unsigned)us << 16);
    }
}

// ------------- K2: LN + pwconv1(MFMA) + GELU -> ws2 (fragment-ordered) ----------
// ws2[blk][q][nt][r][lane]: store instr = 64 lanes x 2B contiguous (128B dense).
__global__ __launch_bounds__(256) void k2_ln_pw1(
    const unsigned short* __restrict__ ws1, const float* __restrict__ ln_w,
    const float* __restrict__ ln_b, const unsigned short* __restrict__ w1t,
    const float* __restrict__ b1, unsigned short* __restrict__ ws2,
    float* __restrict__ partial)
{
    __shared__ unsigned short ly[64*104];
    __shared__ float red1[256], red2[256];
    __shared__ float smu[64], srs[64];
    __shared__ float sq[4][384];
    __shared__ float b1s[384];
    const int tid = threadIdx.x;
    const int p = tid & 63, q = tid >> 6;
    const int n0 = blockIdx.x * 64;
    const int b = n0 / S_;
    const int s0 = n0 - b*S_;
    const size_t basein = (size_t)(b*C_)*S_ + s0 + p;

    for (int i = tid; i < 384; i += 256) b1s[i] = b1[i];

    float v[24];
    float sum=0.f, ssq=0.f;
    #pragma unroll
    for (int i=0;i<24;++i){
        int c = q*24 + i;
        float t = bf2f(ws1[basein + (size_t)c*S_]);
        v[i] = t; sum += t; ssq = fmaf(t,t,ssq);
    }
    red1[tid]=sum; red2[tid]=ssq;
    __syncthreads();
    if (q==0){
        float s1 = red1[p]+red1[64+p]+red1[128+p]+red1[192+p];
        float s2 = red2[p]+red2[64+p]+red2[128+p]+red2[192+p];
        float mu = s1 * (1.f/96.f);
        float var = s2*(1.f/96.f) - mu*mu;
        smu[p]=mu; srs[p]=rsqrtf(var + 1e-6f);
    }
    __syncthreads();
    {
        float mu = smu[p], rs = srs[p];
        #pragma unroll
        for (int i=0;i<24;++i){
            int c = q*24+i;
            ly[p*104 + c] = f2bf((v[i]-mu)*rs*ln_w[c] + ln_b[c]);
        }
    }
    __syncthreads();

    const int lane = tid & 63;
    const int lr = lane & 15;
    const int lk = lane >> 4;
    bf16x8 af[3];
    #pragma unroll
    for (int kk=0;kk<3;++kk)
        af[kk] = *(const bf16x8*)&ly[(q*16 + lr)*104 + kk*32 + lk*8];

    unsigned short* wout = ws2 + (size_t)blockIdx.x*WS2BLK_ + q*6144 + lane;

    for (int nt=0; nt<24; ++nt){
        f32x4 acc = {0.f,0.f,0.f,0.f};
        #pragma unroll
        for (int kk=0;kk<3;++kk){
            bf16x8 bfr = *(const bf16x8*)&w1t[(size_t)(nt*16 + lr)*C_ + kk*32 + lk*8];
            acc = __builtin_amdgcn_mfma_f32_16x16x32_bf16(af[kk], bfr, acc, 0, 0, 0);
        }
        float bias = b1s[nt*16 + lr];
        float ps = 0.f;
        #pragma unroll
        for (int r=0;r<4;++r){
            float val = acc[r] + bias;
            float g = gelu_f(val);
            ps = fmaf(g,g,ps);
            wout[nt*256 + r*64] = f2bf(g);
        }
        ps += __shfl_xor(ps, 16);
        ps += __shfl_xor(ps, 32);
        if (lane < 16) sq[q][nt*16 + lane] = ps;
    }
    __syncthreads();
    // transposed partial: [e][NBLK_]; 2 scattered 4B stores per thread (L2-merged)
    for (int i = tid; i < 384; i += 256)
        partial[(size_t)i*NBLK_ + blockIdx.x] = sq[0][i]+sq[1][i]+sq[2][i]+sq[3][i];
}

// ---------- K3a1: parallel reduce partial[e][NBLK_] -> gx2[b][e] ----------------
// grid (48,2): block handles 8 e-rows; 32 lanes per e, contiguous float4 reads.
__global__ __launch_bounds__(256) void k3a1(
    const float* __restrict__ partial, float* __restrict__ gx2)
{
    const int g = blockIdx.x, b = blockIdx.y;
    const int t = threadIdx.x;
    const int el = t >> 5, lane = t & 31;
    const int e = g*8 + el;
    const float4* row = (const float4*)(partial + (size_t)e*NBLK_ + b*(NBLK_/2));
    float s = 0.f;
    for (int k = lane; k < 294; k += 32){
        float4 v = row[k];
        s += v.x + v.y + v.z + v.w;
    }
    s += __shfl_xor(s, 16);
    s += __shfl_xor(s, 8);
    s += __shfl_xor(s, 4);
    s += __shfl_xor(s, 2);
    s += __shfl_xor(s, 1);
    if (lane == 0) gx2[b*E_ + e] = s;
}

// ---------- K3a2: gx2 -> GRN scale sscale[b][e] ---------------------------------
__global__ __launch_bounds__(384) void k3a2(
    const float* __restrict__ gx2, const float* __restrict__ gamma,
    float* __restrict__ sscale)
{
    const int b = blockIdx.x, e = threadIdx.x;
    float s = fmaxf(gx2[b*E_ + e], 0.f);    // NaN insurance
    float g = sqrtf(s);
    float vsum = g;
    #pragma unroll
    for (int off=32; off; off>>=1) vsum += __shfl_down(vsum, off);
    __shared__ float r[6];
    __shared__ float mean_s;
    if ((e & 63)==0) r[e>>6] = vsum;
    __syncthreads();
    if (e==0) mean_s = (r[0]+r[1]+r[2]+r[3]+r[4]+r[5]) * (1.f/384.f);
    __syncthreads();
    sscale[b*E_ + e] = 1.f + gamma[e] * (g / (mean_s + 1e-6f));
}

// ---------- kw2s: parallel w2s[b][c][e] = w2[e][c]*sscale[b][e] ------------------
__global__ __launch_bounds__(256) void kw2s(
    const float* __restrict__ w2, const float* __restrict__ sscale,
    unsigned short* __restrict__ w2s)
{
    int idx = blockIdx.x*256 + threadIdx.x;   // 288 blocks x 256 = 73728
    int b = idx / (C_*E_);
    int rem = idx - b*(C_*E_);
    int c = rem / E_, e = rem - (rem/E_)*E_;
    w2s[idx] = f2bf(w2[e*C_ + c] * sscale[b*E_ + e]);
}

// ---------- k3c: bc[j] = b2[j] + sum_e beta[e]*w2[e,j], 96 parallel blocks ------
__global__ __launch_bounds__(64) void k3c_bc(
    const float* __restrict__ b2, const float* __restrict__ beta,
    const float* __restrict__ w2, float* __restrict__ bc)
{
    const int j = blockIdx.x, lane = threadIdx.x;
    float a = 0.f;
    #pragma unroll
    for (int r=0;r<6;++r){
        int e = lane*6 + r;
        a = fmaf(beta[e], w2[e*C_ + j], a);
    }
    #pragma unroll
    for (int off=32; off; off>>=1) a += __shfl_down(a, off);
    if (lane==0) bc[j] = b2[j] + a;
}

// ---------- K4: pwconv2 (MFMA), fragment-ordered ws2 reads ----------------------
__global__ __launch_bounds__(256) void k4_pw2(
    const unsigned short* __restrict__ ws2, const unsigned short* __restrict__ w2s,
    const float* __restrict__ bc, const float* __restrict__ x,
    float* __restrict__ out)
{
    const int tid = threadIdx.x;
    const int n0 = blockIdx.x * 128;
    const int b = n0 / S_;
    const int s0 = n0 - b*S_;
    const int lane = tid & 63, q = tid >> 6;
    const int lr = lane & 15, lk = lane >> 4;

    f32x4 acc0[6], acc1[6];
    #pragma unroll
    for (int m=0;m<6;++m){ acc0[m] = (f32x4){0,0,0,0}; acc1[m] = (f32x4){0,0,0,0}; }
    const unsigned short* w2sb = w2s + (size_t)b*C_*E_;
    // fragment-ordered ws2: lane offset within block
    const unsigned short* base0 = ws2 + (size_t)(blockIdx.x*2)*WS2BLK_
                                + q*6144 + (lr&3)*64 + (lr>>2)*16 + (lk&1)*8;

    for (int kk=0; kk<12; ++kk){
        const int off = (2*kk + (lk>>1))*256;
        bf16x8 bfr0 = *(const bf16x8*)&base0[off];
        bf16x8 bfr1 = *(const bf16x8*)&base0[WS2BLK_ + off];
        #pragma unroll
        for (int m=0;m<6;++m){
            bf16x8 afr = *(const bf16x8*)&w2sb[(size_t)(m*16 + lr)*E_ + kk*32 + lk*8];
            acc0[m] = __builtin_amdgcn_mfma_f32_16x16x32_bf16(afr, bfr0, acc0[m], 0, 0, 0);
            acc1[m] = __builtin_amdgcn_mfma_f32_16x16x32_bf16(afr, bfr1, acc1[m], 0, 0, 0);
        }
    }

    const int pos = q*16 + lr;
    const size_t sidx0 = (size_t)s0 + pos;
    #pragma unroll
    for (int m=0;m<6;++m){
        #pragma unroll
        for (int r=0;r<4;++r){
            int c = m*16 + lk*4 + r;
            float bcv = bc[c];
            size_t a0 = ((size_t)(b*C_ + c))*S_ + sidx0;
            out[a0]      = acc0[m][r] + bcv + x[a0];
            out[a0 + 64] = acc1[m][r] + bcv + x[a0 + 64];
        }
    }
}

extern "C" void kernel_launch(void* const* d_in, const int* in_sizes, int n_in,
                              void* d_out, int out_size, void* d_ws, size_t ws_size,
                              hipStream_t stream)
{
    const float* x     = (const float*)d_in[0];
    const float* dwk   = (const float*)d_in[1];
    const float* dwb   = (const float*)d_in[2];
    const float* ln_w  = (const float*)d_in[3];
    const float* ln_b  = (const float*)d_in[4];
    const float* w1    = (const float*)d_in[5];
    const float* b1    = (const float*)d_in[6];
    const float* gamma = (const float*)d_in[7];
    const float* beta  = (const float*)d_in[8];
    const float* w2    = (const float*)d_in[9];
    const float* b2    = (const float*)d_in[10];
    float* out = (float*)d_out;

    char* ws = (char*)d_ws;
    unsigned short* ws1 = (unsigned short*)ws;                        // 28.9 MB used
    unsigned short* ws2 = (unsigned short*)(ws + 57802752);           // 115.6 MB
    unsigned short* w1t = (unsigned short*)(ws + 173408256);          // 73,728 B
    float* sscale = (float*)(ws + 173408256 + 73728);                 // 3,072 B
    float* bc     = sscale + B_*E_;                                   // 384 B
    float* gx2    = bc + C_;                                          // 3,072 B
    // aliased into ws1 region (ws1 dead after k2; written after k2):
    unsigned short* w2s = (unsigned short*)ws;                        // 294,912 B
    // d_out region as scratch (k4 fully overwrites it afterwards):
    float* partial = (float*)d_out;                                   // 3,612,672 B
    unsigned int* pkwg = (unsigned int*)((char*)d_out + 4194304);     // 131,712 B

    kw1t      <<<dim3(144),     256, 0, stream>>>(w1, dwk, w1t, pkwg);
    k1_dwconv <<<dim3(21,96,2), 256, 0, stream>>>(x, pkwg, dwb, ws1);
    k2_ln_pw1 <<<dim3(NBLK_),   256, 0, stream>>>(ws1, ln_w, ln_b, w1t, b1, ws2, partial);
    k3a1      <<<dim3(48,2),    256, 0, stream>>>(partial, gx2);
    k3a2      <<<dim3(2),       384, 0, stream>>>(gx2, gamma, sscale);
    kw2s      <<<dim3(288),     256, 0, stream>>>(w2, sscale, w2s);
    k3c_bc    <<<dim3(96),       64, 0, stream>>>(b2, beta, w2, bc);
    k4_pw2    <<<dim3(N_/128),  256, 0, stream>>>(ws2, w2s, bc, x, out);
}